// Round 5
// baseline (2935.170 us; speedup 1.0000x reference)
//
#include <hip/hip_runtime.h>
#include <stdint.h>
#include <stddef.h>

typedef unsigned short u16;
typedef __attribute__((ext_vector_type(8))) short short8;    // 8 bf16 input frag (4 VGPRs)
typedef __attribute__((ext_vector_type(8))) unsigned short ushort8;
typedef __attribute__((ext_vector_type(4))) unsigned short u16x4;
typedef __attribute__((ext_vector_type(4))) float f32x4;     // MFMA 16x16 accum

#define NTOK 64
#define DIM  512
#define QSTR 36      // q/k/O LDS row stride (u16): 72B rows spread banks
#define REGION 4608  // per-wave LDS u16: q[0:2304) k[2304:4608); O overwrites q
#define XPAD 536     // cvtfrag LDS row stride (u16)

__device__ __forceinline__ float bf2f(u16 u) {
  union { unsigned int i; float f; } x; x.i = ((unsigned int)u) << 16; return x.f;
}
__device__ __forceinline__ u16 f2bf(float f) {
  union { float f; unsigned int i; } x; x.f = f;
  unsigned int u = x.i;
  u += 0x7fffu + ((u >> 16) & 1u);   // RNE
  return (u16)(u >> 16);
}
__device__ __forceinline__ unsigned int pack2(float a, float b) {
  return (unsigned int)f2bf(a) | ((unsigned int)f2bf(b) << 16);
}

// ---------------- dtype detection ----------------
__global__ void detect_k(const u16* __restrict__ w_raw, int* __restrict__ flag) {
  if (threadIdx.x == 0 && blockIdx.x == 0) {
    int cnt = 0;
    for (int i = 0; i < 512; ++i) {
      float v = bf2f(w_raw[i]);
      if (!(v <= 0.5f && v >= -0.5f)) ++cnt;   // counts NaN too
    }
    flag[0] = (cnt > 16) ? 1 : 0;              // 1 = inputs are fp32
  }
}

// ---------------- prep kernels ----------------

__global__ void cvt8_k(const float* __restrict__ fsrc, const u16* __restrict__ usrc,
                       u16* __restrict__ dst, int n, const int* __restrict__ flag) {
  int i = (blockIdx.x * 256 + threadIdx.x) * 8;
  if (i >= n) return;
  if (flag[0]) {
    f32x4 a = *(const f32x4*)(fsrc + i);
    f32x4 b = *(const f32x4*)(fsrc + i + 4);
    ushort8 o;
    #pragma unroll
    for (int e = 0; e < 4; ++e) { o[e] = f2bf(a[e]); o[e + 4] = f2bf(b[e]); }
    *(ushort8*)(dst + i) = o;
  } else {
    *(ushort8*)(dst + i) = *(const ushort8*)(usrc + i);
  }
}

// weight frag-order transform (one-time):
// dst[((nt*16 + ks)*64 + lane)*8 + e] = W[k = ks*32 + (lane>>4)*8 + e][n = nt*16 + (lane&15)]
__global__ void wfrag_k(const float* __restrict__ fsrc, const u16* __restrict__ usrc,
                        u16* __restrict__ dst, int NCOL, const int* __restrict__ flag) {
  int idx = blockIdx.x * 256 + threadIdx.x;   // one elem each; total = NCOL*512
  int e = idx & 7, lane = (idx >> 3) & 63, ks = (idx >> 9) & 15, nt = idx >> 13;
  int n = nt * 16 + (lane & 15);
  int k = ks * 32 + (lane >> 4) * 8 + e;
  size_t src = (size_t)k * NCOL + n;
  dst[idx] = flag[0] ? f2bf(fsrc[src]) : usrc[src];
}

// per-window frag-order x transform: one block (256 thr) per window.
__global__ __launch_bounds__(256) void cvtfrag_k(
    const float* __restrict__ fsrc, const u16* __restrict__ usrc,
    u16* __restrict__ xf, const int* __restrict__ flag)
{
  __shared__ __attribute__((aligned(16))) u16 xl[64 * XPAD];
  const int t = threadIdx.x;
  const size_t wbase = (size_t)blockIdx.x * (NTOK * DIM);

  if (flag[0]) {
    #pragma unroll
    for (int c = 0; c < 32; ++c) {
      int i = c * 1024 + t * 4;
      f32x4 v = *(const f32x4*)(fsrc + wbase + i);
      int tok = i >> 9, k = i & 511;
      u16x4 o;
      #pragma unroll
      for (int e = 0; e < 4; ++e) o[e] = f2bf(v[e]);
      *(u16x4*)&xl[tok * XPAD + k] = o;
    }
  } else {
    #pragma unroll
    for (int c = 0; c < 16; ++c) {
      int i = c * 2048 + t * 8;
      ushort8 v = *(const ushort8*)(usrc + wbase + i);
      int tok = i >> 9, k = i & 511;
      *(ushort8*)&xl[tok * XPAD + k] = v;
    }
  }
  __syncthreads();

  u16* dst = xf + wbase;
  #pragma unroll
  for (int j = 0; j < 16; ++j) {
    int idx8 = j * 256 + t;
    int lane = idx8 & 63, mi = (idx8 >> 6) & 3, ks = idx8 >> 8;
    int tok = mi * 16 + (lane & 15);
    int k = ks * 32 + (lane >> 4) * 8;
    ushort8 v = *(const ushort8*)&xl[tok * XPAD + k];
    *(ushort8*)(dst + (size_t)idx8 * 8) = v;
  }
}

// swapped-S bias expansion:
// biasc[h][mi][ni][lane][r] = table[h, n-part, m-part] with
// n (query) = mi*16 + (lane&15), m (key) = ni*16 + (lane>>4)*4 + r
__global__ void bias_expand_k(const float* __restrict__ ftab, const u16* __restrict__ utab,
                              float* __restrict__ biasc, const int* __restrict__ flag) {
  int t = blockIdx.x * 256 + threadIdx.x;   // 65536 total
  int r    = t & 3;
  int lane = (t >> 2) & 63;
  int ni   = (t >> 8) & 3;
  int mi   = (t >> 10) & 3;
  int h    = t >> 12;
  int n = mi * 16 + (lane & 15);            // query row
  int m = ni * 16 + (lane >> 4) * 4 + r;    // key col
  int i1 = n >> 3, j1 = n & 7, i2 = m >> 3, j2 = m & 7;
  int off = h * 225 + (i1 - i2 + 7) * 15 + (j1 - j2 + 7);
  if (flag[0]) biasc[t] = ftab[off];
  else         biasc[t] = bf2f(utab[off]);
}

// ---------------- fully fused per-window kernel ----------------
// One block = one 64-token window. 8 waves; round r: wave w owns head h=r*8+w.
// Swapped QK^T (S^T in regs, query=lane&15): softmax lane-local + 2 shfl rounds.
// P and V never touch LDS: bf16-packed in-register, redistributed to MFMA frag
// layout via 4-lane-group shfl exchange. LDS = q,k only (73.7 KB) -> 2 blocks/CU.
__global__ __launch_bounds__(512, 4) void fused_k(
    const u16* __restrict__ xf,       // [win][16][4][64][8] frag-order bf16 x
    const u16* __restrict__ wqf,      // frag-order wqkv
    const u16* __restrict__ bqc,      // [1536]
    const float* __restrict__ biasc,  // [16][4][4][64][4] (swapped-S layout)
    const u16* __restrict__ wpf,      // frag-order wproj
    const u16* __restrict__ bpc,      // [512]
    const int* __restrict__ flag,
    u16* __restrict__ outU, float* __restrict__ outF)
{
  __shared__ __attribute__((aligned(16))) u16 lds[8][REGION];   // 73,728 B

  const int lane = threadIdx.x & 63;
  const int wave = threadIdx.x >> 6;     // 0..7
  const int lr = lane & 15, quad = lane >> 4;
  const int blk = blockIdx.x;

  u16* ql = &lds[wave][0];
  u16* kl = &lds[wave][2304];
  u16* Ol = &lds[wave][0];       // O_h[64][QSTR] overwrites q (dead after S)

  const u16* xw = xf + (size_t)blk * (NTOK * DIM) + lane * 8;
  const float SCALE = 0.17677669529663687f;   // 32^-0.5
  const float L2E = 1.44269504088896f;
  const f32x4 zero4 = {0.f, 0.f, 0.f, 0.f};

  // exchange constants (4-lane column group {lr, lr+16, lr+32, lr+48})
  const int src1 = lr + ((quad & 1) << 5);   // quad 2*(quad&1)
  const int src2 = src1 + 16;
  const bool hiq = quad >= 2;

  // persistent projection accumulators: out[64][wave*64 .. +64]
  f32x4 acc[4][4];
  #pragma unroll
  for (int mi = 0; mi < 4; ++mi)
    #pragma unroll
    for (int ni = 0; ni < 4; ++ni) acc[mi][ni] = zero4;

  for (int r = 0; r < 2; ++r) {
    const int h = r * 8 + wave;

    // ---- qkv GEMM for head h: M=64, N=96 (q|k|v x 2 col-tiles), K=512 ----
    f32x4 aq[4][2], ak[4][2], av[4][2];
    #pragma unroll
    for (int mi = 0; mi < 4; ++mi) {
      aq[mi][0] = zero4; aq[mi][1] = zero4;
      ak[mi][0] = zero4; ak[mi][1] = zero4;
      av[mi][0] = zero4; av[mi][1] = zero4;
    }
    const u16* wb = wqf + (size_t)(h * 2) * 8192 + lane * 8;
    #pragma unroll 4
    for (int ks = 0; ks < 16; ++ks) {
      short8 af[4];
      #pragma unroll
      for (int mi = 0; mi < 4; ++mi)
        af[mi] = *(const short8*)(xw + (ks * 4 + mi) * 512);
      short8 b0 = *(const short8*)(wb + ks * 512);                 // q j=0
      short8 b1 = *(const short8*)(wb + 8192 + ks * 512);          // q j=1
      short8 b2 = *(const short8*)(wb + 32 * 8192 + ks * 512);     // k j=0
      short8 b3 = *(const short8*)(wb + 33 * 8192 + ks * 512);     // k j=1
      short8 b4 = *(const short8*)(wb + 64 * 8192 + ks * 512);     // v j=0
      short8 b5 = *(const short8*)(wb + 65 * 8192 + ks * 512);     // v j=1
      #pragma unroll
      for (int mi = 0; mi < 4; ++mi) {
        aq[mi][0] = __builtin_amdgcn_mfma_f32_16x16x32_bf16(af[mi], b0, aq[mi][0], 0, 0, 0);
        aq[mi][1] = __builtin_amdgcn_mfma_f32_16x16x32_bf16(af[mi], b1, aq[mi][1], 0, 0, 0);
        ak[mi][0] = __builtin_amdgcn_mfma_f32_16x16x32_bf16(af[mi], b2, ak[mi][0], 0, 0, 0);
        ak[mi][1] = __builtin_amdgcn_mfma_f32_16x16x32_bf16(af[mi], b3, ak[mi][1], 0, 0, 0);
        av[mi][0] = __builtin_amdgcn_mfma_f32_16x16x32_bf16(af[mi], b4, av[mi][0], 0, 0, 0);
        av[mi][1] = __builtin_amdgcn_mfma_f32_16x16x32_bf16(af[mi], b5, av[mi][1], 0, 0, 0);
      }
    }

    // q (scaled+bias), k (+bias) -> LDS stride QSTR; C-layout tok = mi*16+quad*4+e
    #pragma unroll
    for (int j = 0; j < 2; ++j) {
      float bq = bf2f(bqc[h * 32 + j * 16 + lr]);
      float bk = bf2f(bqc[512 + h * 32 + j * 16 + lr]);
      #pragma unroll
      for (int mi = 0; mi < 4; ++mi)
        #pragma unroll
        for (int e = 0; e < 4; ++e) {
          int tok = mi * 16 + quad * 4 + e;
          int d = j * 16 + lr;
          ql[tok * QSTR + d] = f2bf((aq[mi][j][e] + bq) * SCALE);
          kl[tok * QSTR + d] = f2bf(ak[mi][j][e] + bk);
        }
    }

    // v: bias + bf16-pack in-register. pkv[jt][mi'][w] holds toks mi'*16+quad*4+{2w,2w+1},
    // d = jt*16+lr.
    unsigned int pkv[2][4][2];
    {
      float bv0 = bf2f(bqc[1024 + h * 32 + lr]);
      float bv1 = bf2f(bqc[1024 + h * 32 + 16 + lr]);
      #pragma unroll
      for (int mi = 0; mi < 4; ++mi)
        #pragma unroll
        for (int w = 0; w < 2; ++w) {
          pkv[0][mi][w] = pack2(av[mi][0][2 * w] + bv0, av[mi][0][2 * w + 1] + bv0);
          pkv[1][mi][w] = pack2(av[mi][1][2 * w] + bv1, av[mi][1][2 * w + 1] + bv1);
        }
    }

    // ---- S^T = K @ Q^T : s[ni][mi], C-layout col=lr=query, row=quad*4+e=key ----
    f32x4 s[4][4];
    {
      short8 afk[4], bfq[4];
      #pragma unroll
      for (int t = 0; t < 4; ++t)
        afk[t] = *(const short8*)&kl[(t * 16 + lr) * QSTR + quad * 8];
      #pragma unroll
      for (int t = 0; t < 4; ++t)
        bfq[t] = *(const short8*)&ql[(t * 16 + lr) * QSTR + quad * 8];
      #pragma unroll
      for (int ni = 0; ni < 4; ++ni)
        #pragma unroll
        for (int mi = 0; mi < 4; ++mi)
          s[ni][mi] = __builtin_amdgcn_mfma_f32_16x16x32_bf16(afk[ni], bfq[mi], zero4, 0, 0, 0);
    }

    // bias + softmax (per query mi: 16 lane-local vals + shfl_xor 16,32) + pack P
    float ssum[4];
    unsigned int pk[4][4][2];   // [mi][ni][w]
    #pragma unroll
    for (int mi = 0; mi < 4; ++mi) {
      #pragma unroll
      for (int ni = 0; ni < 4; ++ni) {
        f32x4 bb = *(const f32x4*)&biasc[((((h * 4 + mi) * 4 + ni) * 64) + lane) * 4];
        s[ni][mi] = s[ni][mi] + bb;
      }
      f32x4 m4 = s[0][mi];
      #pragma unroll
      for (int ni = 1; ni < 4; ++ni)
        #pragma unroll
        for (int e = 0; e < 4; ++e) m4[e] = fmaxf(m4[e], s[ni][mi][e]);
      float mm = fmaxf(fmaxf(m4[0], m4[1]), fmaxf(m4[2], m4[3]));
      mm = fmaxf(mm, __shfl_xor(mm, 16, 64));
      mm = fmaxf(mm, __shfl_xor(mm, 32, 64));
      #pragma unroll
      for (int ni = 0; ni < 4; ++ni)
        #pragma unroll
        for (int e = 0; e < 4; ++e)
          s[ni][mi][e] = exp2f((s[ni][mi][e] - mm) * L2E);
      f32x4 s4 = s[0][mi] + s[1][mi] + s[2][mi] + s[3][mi];
      float sm = (s4[0] + s4[1]) + (s4[2] + s4[3]);
      sm += __shfl_xor(sm, 16, 64);
      sm += __shfl_xor(sm, 32, 64);
      ssum[mi] = sm;
      #pragma unroll
      for (int ni = 0; ni < 4; ++ni)
        #pragma unroll
        for (int w = 0; w < 2; ++w)
          pk[mi][ni][w] = pack2(s[ni][mi][2 * w], s[ni][mi][2 * w + 1]);
    }

    // ---- O = P @ V via in-register frag exchange; M=64, N=32, K=64 (2 k-steps) ----
    f32x4 o[4][2];
    #pragma unroll
    for (int mi = 0; mi < 4; ++mi) { o[mi][0] = zero4; o[mi][1] = zero4; }
    #pragma unroll
    for (int ks = 0; ks < 2; ++ks) {
      short8 bvf[2];
      #pragma unroll
      for (int n2 = 0; n2 < 2; ++n2) {
        union { short8 v; unsigned int w[4]; } u;
        unsigned int a, b;
        a = __shfl((int)pkv[n2][2 * ks][0], src1, 64);
        b = __shfl((int)pkv[n2][2 * ks + 1][0], src1, 64);
        u.w[0] = hiq ? b : a;
        a = __shfl((int)pkv[n2][2 * ks][1], src1, 64);
        b = __shfl((int)pkv[n2][2 * ks + 1][1], src1, 64);
        u.w[1] = hiq ? b : a;
        a = __shfl((int)pkv[n2][2 * ks][0], src2, 64);
        b = __shfl((int)pkv[n2][2 * ks + 1][0], src2, 64);
        u.w[2] = hiq ? b : a;
        a = __shfl((int)pkv[n2][2 * ks][1], src2, 64);
        b = __shfl((int)pkv[n2][2 * ks + 1][1], src2, 64);
        u.w[3] = hiq ? b : a;
        bvf[n2] = u.v;
      }
      #pragma unroll
      for (int mi = 0; mi < 4; ++mi) {
        union { short8 v; unsigned int w[4]; } u;
        unsigned int a, b;
        a = __shfl((int)pk[mi][2 * ks][0], src1, 64);
        b = __shfl((int)pk[mi][2 * ks + 1][0], src1, 64);
        u.w[0] = hiq ? b : a;
        a = __shfl((int)pk[mi][2 * ks][1], src1, 64);
        b = __shfl((int)pk[mi][2 * ks + 1][1], src1, 64);
        u.w[1] = hiq ? b : a;
        a = __shfl((int)pk[mi][2 * ks][0], src2, 64);
        b = __shfl((int)pk[mi][2 * ks + 1][0], src2, 64);
        u.w[2] = hiq ? b : a;
        a = __shfl((int)pk[mi][2 * ks][1], src2, 64);
        b = __shfl((int)pk[mi][2 * ks + 1][1], src2, 64);
        u.w[3] = hiq ? b : a;
        o[mi][0] = __builtin_amdgcn_mfma_f32_16x16x32_bf16(u.v, bvf[0], o[mi][0], 0, 0, 0);
        o[mi][1] = __builtin_amdgcn_mfma_f32_16x16x32_bf16(u.v, bvf[1], o[mi][1], 0, 0, 0);
      }
    }

    // normalize (transpose sums into o's C-layout) + O_h -> LDS [tok][d] stride QSTR
    #pragma unroll
    for (int mi = 0; mi < 4; ++mi) {
      f32x4 rs;
      #pragma unroll
      for (int e = 0; e < 4; ++e) {
        float sv = __shfl(ssum[mi], (quad * 4 + e) + (lane & 48), 64);
        rs[e] = __builtin_amdgcn_rcpf(sv);
      }
      #pragma unroll
      for (int n2 = 0; n2 < 2; ++n2)
        #pragma unroll
        for (int e = 0; e < 4; ++e) {
          int tok = mi * 16 + quad * 4 + e;
          int d = n2 * 16 + lr;
          Ol[tok * QSTR + d] = f2bf(o[mi][n2][e] * rs[e]);
        }
    }

    __syncthreads();   // all O_h visible

    // ---- proj accumulate: out[:, wave*64..+64] += O_h2 @ Wproj[h2*32.., :] ----
    const u16* wpb = wpf + (size_t)(wave * 4) * 8192 + lane * 8;
    #pragma unroll 2
    for (int w2 = 0; w2 < 8; ++w2) {
      const u16* Ow = &lds[w2][0];
      const int h2 = r * 8 + w2;
      short8 afO[4], bfW[4];
      #pragma unroll
      for (int mi = 0; mi < 4; ++mi)
        afO[mi] = *(const short8*)&Ow[(mi * 16 + lr) * QSTR + quad * 8];
      #pragma unroll
      for (int ni = 0; ni < 4; ++ni)
        bfW[ni] = *(const short8*)(wpb + ni * 8192 + h2 * 512);
      #pragma unroll
      for (int mi = 0; mi < 4; ++mi)
        #pragma unroll
        for (int ni = 0; ni < 4; ++ni)
          acc[mi][ni] = __builtin_amdgcn_mfma_f32_16x16x32_bf16(afO[mi], bfW[ni], acc[mi][ni], 0, 0, 0);
    }
    __syncthreads();   // O regions reusable next round
  }

  // ---- epilogue: out = acc + b_proj ----
  const int f32o = flag[0];
  if (f32o) {
    // LDS bounce in two 32-row passes for coalesced float4 global writes
    float* lf = (float*)&lds[0][0];   // 64 KB of the 73.7 KB
    #pragma unroll
    for (int pass = 0; pass < 2; ++pass) {
      __syncthreads();
      #pragma unroll
      for (int mi2 = 0; mi2 < 2; ++mi2) {
        int mi = pass * 2 + mi2;
        #pragma unroll
        for (int ni = 0; ni < 4; ++ni) {
          int col = wave * 64 + ni * 16 + lr;
          float bv = bf2f(bpc[col]);
          #pragma unroll
          for (int e = 0; e < 4; ++e) {
            int row = mi2 * 16 + quad * 4 + e;
            lf[row * 512 + col] = acc[mi][ni][e] + bv;
          }
        }
      }
      __syncthreads();
      const size_t rowbase = (size_t)(blk * NTOK + pass * 32) * DIM;
      #pragma unroll
      for (int c = 0; c < 8; ++c) {
        int i = c * 2048 + threadIdx.x * 4;
        *(f32x4*)(outF + rowbase + i) = *(const f32x4*)(lf + i);
      }
    }
  } else {
    #pragma unroll
    for (int ni = 0; ni < 4; ++ni) {
      int col = wave * 64 + ni * 16 + lr;
      float bv = bf2f(bpc[col]);
      #pragma unroll
      for (int mi = 0; mi < 4; ++mi) {
        size_t rowb = (size_t)(blk * NTOK + mi * 16 + quad * 4);
        #pragma unroll
        for (int e = 0; e < 4; ++e)
          outU[(rowb + e) * (size_t)DIM + col] = f2bf(acc[mi][ni][e] + bv);
      }
    }
  }
}

// ---------------- launch ----------------

extern "C" void kernel_launch(void* const* d_in, const int* in_sizes, int n_in,
                              void* d_out, int out_size, void* d_ws, size_t ws_size,
                              hipStream_t stream)
{
  (void)in_sizes; (void)n_in; (void)out_size;

  const void* x      = d_in[0];   // [2048*64][512]
  const void* w_qkv  = d_in[1];   // [512][1536]
  const void* b_qkv  = d_in[2];   // [1536]
  const void* table  = d_in[3];   // [16][15][15]
  const void* w_proj = d_in[4];   // [512][512]
  const void* b_proj = d_in[5];   // [512]

  char* ws = (char*)d_ws;
  size_t off = 0;
  auto alloc = [&](size_t bytes) -> char* {
    char* p = ws + off; off += (bytes + 255) & ~(size_t)255; return p;
  };
  u16*   wqf    = (u16*)alloc(1572864);   // frag-order wqkv
  u16*   wpf    = (u16*)alloc(524288);    // frag-order wproj
  float* biasc  = (float*)alloc(262144);
  u16*   bqc    = (u16*)alloc(3072);
  u16*   bpc    = (u16*)alloc(1024);
  int*   flag   = (int*)alloc(256);
  size_t fixed  = off;

  int win = 2048;                        // windows per chunk
  while (win > 2 && fixed + (size_t)win * 65536 > ws_size) win >>= 1;
  const int mc = win * 64;               // rows per chunk
  u16* xfC = (u16*)alloc((size_t)mc * 512 * 2);   // frag-order x chunk

  detect_k<<<dim3(1), dim3(64), 0, stream>>>((const u16*)w_qkv, flag);
  wfrag_k<<<dim3(3072), dim3(256), 0, stream>>>((const float*)w_qkv, (const u16*)w_qkv, wqf, 1536, flag);
  wfrag_k<<<dim3(1024), dim3(256), 0, stream>>>((const float*)w_proj, (const u16*)w_proj, wpf, 512, flag);
  bias_expand_k<<<dim3(256), dim3(256), 0, stream>>>((const float*)table, (const u16*)table, biasc, flag);
  cvt8_k<<<dim3(1), dim3(256), 0, stream>>>((const float*)b_qkv, (const u16*)b_qkv, bqc, 1536, flag);
  cvt8_k<<<dim3(1), dim3(256), 0, stream>>>((const float*)b_proj, (const u16*)b_proj, bpc, 512, flag);

  const int nchunk = 2048 / win;
  for (int c = 0; c < nchunk; ++c) {
    size_t base = (size_t)c * mc * 512;   // element offset into x / out

    cvtfrag_k<<<dim3(win), dim3(256), 0, stream>>>(
        (const float*)x + base, (const u16*)x + base, xfC, flag);

    fused_k<<<dim3(win), dim3(512), 0, stream>>>(
        xfC, wqf, bqc, biasc, wpf, bpc, flag,
        (u16*)d_out + base, (float*)d_out + base);
  }
}